// Round 20
// baseline (152.261 us; speedup 1.0000x reference)
//
#include <hip/hip_runtime.h>
#include <hip/hip_bf16.h>

#define Hh 50

typedef __attribute__((ext_vector_type(8))) short bf16x8;
typedef __attribute__((ext_vector_type(4))) float f32x4;

static __device__ __forceinline__ short b16(float x) {
    return __builtin_bit_cast(short, __float2bfloat16(x));
}
static __device__ __forceinline__ bf16x8 cvt8(const float* p) {
    f32x4 a = *(const f32x4*)p;
    f32x4 b = *(const f32x4*)(p + 4);
    bf16x8 r;
    r[0] = b16(a[0]); r[1] = b16(a[1]); r[2] = b16(a[2]); r[3] = b16(a[3]);
    r[4] = b16(b[0]); r[5] = b16(b[1]); r[6] = b16(b[2]); r[7] = b16(b[3]);
    return r;
}
// async global->LDS, 16B per lane; LDS dest = uniform base + lane*16 (m03/m97)
static __device__ __forceinline__ void gload_lds16(const void* g, void* l) {
    __builtin_amdgcn_global_load_lds(
        (const __attribute__((address_space(1))) unsigned int*)g,
        (__attribute__((address_space(3))) unsigned int*)l, 16, 0, 0);
}

// -------- Kernel 0: pack wh_w into 16x16x32 B-fragment order, replicated 8x --------
// whpk[c*65536 + ((p*8+ks)*64+l)*8+j] = bf16(wh_w[p*16+(l&15)][ks*32+(l>>4)*8+j])
__global__ __launch_bounds__(256) void k_prep(const float* __restrict__ w,
                                              short* __restrict__ o) {
    int t = (int)blockIdx.x * 256 + threadIdx.x;   // 0..8191
    int p  = t >> 9;
    int ks = (t >> 6) & 7;
    int l  = t & 63;
    int col = p * 16 + (l & 15);
    int k   = ks * 32 + (l >> 4) * 8;
    bf16x8 v = cvt8(w + (size_t)col * 256 + k);
#pragma unroll
    for (int c = 0; c < 8; c++)
        *(bf16x8*)(o + (size_t)c * 65536 + (size_t)t * 8) = v;
}

// ---------------- Kernel 1: wcplus[4096][256] (f32) = cur @ wc_w^T + wc_b + wh_b ------
__global__ __launch_bounds__(64) void k_wc(const float* __restrict__ cur,
                                           const float* __restrict__ wcw,
                                           const float* __restrict__ wcb,
                                           const float* __restrict__ whb,
                                           float* __restrict__ out) {
    int l = threadIdx.x;
    int m0 = (int)(blockIdx.x >> 2) * 16;
    int ntb = (int)(blockIdx.x & 3) * 4;
    int lk = (l >> 4) * 8;

    bf16x8 Af[8];
#pragma unroll
    for (int k = 0; k < 8; k++)
        Af[k] = cvt8(cur + (size_t)(m0 + (l & 15)) * 256 + k * 32 + lk);

#pragma unroll
    for (int nt = 0; nt < 4; nt++) {
        int col = (ntb + nt) * 16 + (l & 15);
        f32x4 a = {0.f, 0.f, 0.f, 0.f};
#pragma unroll
        for (int k = 0; k < 8; k++) {
            bf16x8 Bf = cvt8(wcw + (size_t)col * 256 + k * 32 + lk);
            a = __builtin_amdgcn_mfma_f32_16x16x32_bf16(Af[k], Bf, a, 0, 0, 0);
        }
        float bias = wcb[col] + whb[col];
        int row = m0 + (l >> 4) * 4;
#pragma unroll
        for (int r = 0; r < 4; r++)
            out[(size_t)(row + r) * 256 + col] = a[r] + bias;
    }
}

// ---------------- Kernel 2: flat GEMM (m97 pattern) + sigmoid/qt epilogue -> alpha ----
// M = 204800 flat hist rows. Block = 128 rows x 128 cols (col-half ch), 512 thr = 8 waves
// (4 mh x 2 nh; wave = 32 rows x 64 cols, acc[2][4] = 8 chains). K-loop: 4 chunks of 64,
// double-buffered: B via global_load_lds into linear frag-layout LDS (16 KB/chunk),
// A reg-staged f32->bf16 into XOR-swizzled LDS (16 KB/chunk). Partial alpha (sum over
// this block's 128 cols) written non-atomically to aws[ch][row].
__global__ __launch_bounds__(512, 4)
void k_alpha(const float* __restrict__ hist,
             const float* __restrict__ wcplus,
             const short* __restrict__ whpk,
             const float* __restrict__ qtw,
             float* __restrict__ aws) {
    __shared__ __align__(16) char Ab[2][16384];   // [row 0..127][g3 0..7] XOR-swizzled
    __shared__ __align__(16) char Bb[2][16384];   // 16 frags x 1 KB, linear
    __shared__ float alphaP[2][128];

    int tid = threadIdx.x;
    int l = tid & 63;
    int w = tid >> 6;              // 0..7
    int mh = w >> 1, nh = w & 1;
    int rt = (int)(blockIdx.x >> 1);
    int ch = (int)(blockIdx.x & 1);
    int R0 = rt * 128;
    int bh = R0 >> 9;
    int b  = bh / Hh;
    int s0 = R0 & 511;
    const short* whq = whpk + (size_t)(rt & 7) * 65536;

    // A-stage: chunk c (k in [c*64, c*64+64)) -> Ab[buf], swizzled
    auto stageA = [&](int buf, int c) {
#pragma unroll
        for (int p2 = 0; p2 < 2; p2++) {
            int i = tid + p2 * 512;            // 0..1023
            int row = i >> 3, g3 = i & 7;
            bf16x8 v = cvt8(hist + (size_t)(R0 + row) * 256 + c * 64 + g3 * 8);
            *(bf16x8*)(&Ab[buf][row * 128 + ((g3 ^ (row & 7)) << 4)]) = v;
        }
    };
    // B-stage: wave w DMAs its col-panel's 2 frags for chunk c -> Bb[buf] (linear)
    auto stageB = [&](int buf, int c) {
        int p = ch * 8 + w;
#pragma unroll
        for (int ksl = 0; ksl < 2; ksl++) {
            const short* g = whq + ((size_t)((p * 8 + c * 2 + ksl) * 64 + l)) * 8;
            gload_lds16(g, &Bb[buf][(w * 2 + ksl) * 1024]);
        }
    };

    stageB(0, 0);
    stageA(0, 0);
    __syncthreads();

    f32x4 acc[2][4];
#pragma unroll
    for (int mi = 0; mi < 2; mi++)
#pragma unroll
        for (int nt = 0; nt < 4; nt++)
            acc[mi][nt] = (f32x4){0.f, 0.f, 0.f, 0.f};

#pragma unroll 1
    for (int c = 0; c < 4; c++) {
        int buf = c & 1;
        if (c < 3) {
            stageB(buf ^ 1, c + 1);
            stageA(buf ^ 1, c + 1);
        }
#pragma unroll
        for (int ksl = 0; ksl < 2; ksl++) {
            bf16x8 Am[2], Bf[4];
#pragma unroll
            for (int mi = 0; mi < 2; mi++) {
                int rA = mh * 32 + mi * 16 + (l & 15);
                int g3 = ksl * 4 + (l >> 4);
                Am[mi] = *(const bf16x8*)(&Ab[buf][rA * 128 + ((g3 ^ (rA & 7)) << 4)]);
            }
#pragma unroll
            for (int nt = 0; nt < 4; nt++)
                Bf[nt] = *(const bf16x8*)(&Bb[buf][((nh * 4 + nt) * 2 + ksl) * 1024 + l * 16]);
#pragma unroll
            for (int mi = 0; mi < 2; mi++)
#pragma unroll
                for (int nt = 0; nt < 4; nt++)
                    acc[mi][nt] = __builtin_amdgcn_mfma_f32_16x16x32_bf16(
                        Am[mi], Bf[nt], acc[mi][nt], 0, 0, 0);
        }
        __syncthreads();
    }

    // ---- epilogue: bias gather + sigmoid + qt, partial over this block's 128 cols ----
    float qv[4];
#pragma unroll
    for (int nt = 0; nt < 4; nt++)
        qv[nt] = qtw[ch * 128 + nh * 64 + nt * 16 + (l & 15)];

    float pal[2][4];
#pragma unroll
    for (int mi = 0; mi < 2; mi++)
#pragma unroll
        for (int r = 0; r < 4; r++) pal[mi][r] = 0.f;

#pragma unroll
    for (int mi = 0; mi < 2; mi++)
#pragma unroll
        for (int nt = 0; nt < 4; nt++) {
            int col = ch * 128 + nh * 64 + nt * 16 + (l & 15);
#pragma unroll
            for (int r = 0; r < 4; r++) {
                int rl = mh * 32 + mi * 16 + (l >> 4) * 4 + r;
                float bias = wcplus[(size_t)(b * 512 + s0 + rl) * 256 + col];
                float v = acc[mi][nt][r] + bias;
                pal[mi][r] += qv[nt] * __builtin_amdgcn_rcpf(1.0f + __expf(-v));
            }
        }

#pragma unroll
    for (int mi = 0; mi < 2; mi++)
#pragma unroll
        for (int r = 0; r < 4; r++) {
            float v = pal[mi][r];
            v += __shfl_xor(v, 1);
            v += __shfl_xor(v, 2);
            v += __shfl_xor(v, 4);
            v += __shfl_xor(v, 8);
            if ((l & 15) == 0)
                alphaP[nh][mh * 32 + mi * 16 + (l >> 4) * 4 + r] = v;
        }
    __syncthreads();
    if (tid < 128)
        aws[(size_t)ch * 204800 + R0 + tid] = alphaP[0][tid] + alphaP[1][tid];
}

// ---------------- Kernel 3: hsum[b,s,:] = sum_h alpha[b,h,s] * hist[b,h,s,:] ----------
// Block = (b, 4 consecutive s); alpha = qtb + aws[0] + aws[1] staged in LDS.
__global__ __launch_bounds__(256, 8)
void k_hsum(const float* __restrict__ hist,
            const float* __restrict__ aws,
            const float* __restrict__ qtb,
            float* __restrict__ hsum) {
    __shared__ float al[Hh * 4];
    int tid = threadIdx.x;
    int b = (int)(blockIdx.x >> 7);
    int s0 = (int)(blockIdx.x & 127) * 4;

    if (tid < Hh * 4) {
        int h = tid >> 2, si = tid & 3;
        size_t row = (size_t)(b * Hh + h) * 512 + s0 + si;
        al[tid] = qtb[0] + aws[row] + aws[204800 + row];
    }
    __syncthreads();

    int sl = tid >> 6;
    int d4 = (tid & 63) * 4;
    const float* hp = hist + ((size_t)(b * Hh) * 512 + s0 + sl) * 256 + d4;
    f32x4 a = {0.f, 0.f, 0.f, 0.f};
#pragma unroll 2
    for (int h = 0; h < Hh; h++) {
        f32x4 v = *(const f32x4*)(hp + (size_t)h * 512 * 256);
        float av = al[h * 4 + sl];
        a[0] += av * v[0]; a[1] += av * v[1];
        a[2] += av * v[2]; a[3] += av * v[3];
    }
    *(f32x4*)(hsum + ((size_t)(b * 512) + s0 + sl) * 256 + d4) = a;
}

// ---------------- Kernel 4: out[4096][128] (f32) = [cur, hsum] @ wf_w^T + wf_b --------
__global__ __launch_bounds__(64) void k_wf(const float* __restrict__ cur,
                                           const float* __restrict__ hsum,
                                           const float* __restrict__ wfw,
                                           const float* __restrict__ wfb,
                                           float* __restrict__ out) {
    int l = threadIdx.x;
    int m0 = (int)(blockIdx.x >> 1) * 16;
    int ntb = (int)(blockIdx.x & 1) * 4;
    int lk = (l >> 4) * 8;

    f32x4 acc[4];
#pragma unroll
    for (int nt = 0; nt < 4; nt++) acc[nt] = (f32x4){0.f, 0.f, 0.f, 0.f};

#pragma unroll
    for (int k = 0; k < 16; k++) {
        int row = m0 + (l & 15);
        bf16x8 Af;
        if (k < 8)
            Af = cvt8(cur + (size_t)row * 256 + k * 32 + lk);
        else
            Af = cvt8(hsum + (size_t)row * 256 + (k - 8) * 32 + lk);
#pragma unroll
        for (int nt = 0; nt < 4; nt++) {
            int col = (ntb + nt) * 16 + (l & 15);
            bf16x8 Bf = cvt8(wfw + (size_t)col * 512 + k * 32 + lk);
            acc[nt] = __builtin_amdgcn_mfma_f32_16x16x32_bf16(Af, Bf, acc[nt], 0, 0, 0);
        }
    }
#pragma unroll
    for (int nt = 0; nt < 4; nt++) {
        int col = (ntb + nt) * 16 + (l & 15);
        float bias = wfb[col];
        int row = m0 + (l >> 4) * 4;
#pragma unroll
        for (int r = 0; r < 4; r++)
            out[(size_t)(row + r) * 128 + col] = acc[nt][r] + bias;
    }
}

extern "C" void kernel_launch(void* const* d_in, const int* in_sizes, int n_in,
                              void* d_out, int out_size, void* d_ws, size_t ws_size,
                              hipStream_t stream) {
    const float* hist = (const float*)d_in[0];
    const float* cur  = (const float*)d_in[1];
    const float* wc_w = (const float*)d_in[2];
    const float* wc_b = (const float*)d_in[3];
    const float* wh_w = (const float*)d_in[4];
    const float* wh_b = (const float*)d_in[5];
    const float* qt_w = (const float*)d_in[6];
    const float* qt_b = (const float*)d_in[7];
    const float* wf_w = (const float*)d_in[8];
    const float* wf_b = (const float*)d_in[9];

    float* wc_ws = (float*)d_ws;                                       // 4 MB (wcplus)
    float* hsum  = (float*)((char*)d_ws + ((size_t)4 << 20));          // 4 MB
    short* whpk  = (short*)((char*)d_ws + ((size_t)8 << 20));          // 1 MB (8 replicas)
    float* aws   = (float*)((char*)d_ws + ((size_t)9 << 20));          // 1.6 MB partials

    k_prep<<<32, 256, 0, stream>>>(wh_w, whpk);
    k_wc<<<1024, 64, 0, stream>>>(cur, wc_w, wc_b, wh_b, wc_ws);
    k_alpha<<<3200, 512, 0, stream>>>(hist, wc_ws, whpk, qt_w, aws);
    k_hsum<<<1024, 256, 0, stream>>>(hist, aws, qt_b, hsum);
    k_wf<<<512, 64, 0, stream>>>(cur, hsum, wf_w, wf_b, (float*)d_out);
}